// Round 9
// baseline (476.714 us; speedup 1.0000x reference)
//
#include <hip/hip_runtime.h>
#include <stdint.h>

static constexpr int kN = 128;
static constexpr int kTri = (kN * (kN - 1)) / 2;  // strict upper triangle: 8128 cells
static constexpr int kThreads = 1024;
static constexpr int kSmallK = 16;   // k <= this: one row per lane, no reduction
static constexpr float kNeg = -9999.0f;
static constexpr float kThresh = -9000.0f;
static constexpr float kArcBonus = 5.0f;
static constexpr int kDynLds = 4 * kTri * (int)sizeof(float);  // 130,048 B

__device__ __forceinline__ int rowBase(int i) { return (i * (2 * kN - 1 - i)) / 2; }
__device__ __forceinline__ int colBase(int j) { return (j * (j - 1)) / 2; }

// LDS: s01 (row-major), s01T (col-major), s11 (row-major), s11T (col-major).
// Global scratch: s00g (col reads, VMEM pipe), s10g (row reads, coalesced), wsBT.
// All chart writes unconditional (select with kNeg) => no init pass needed:
// every read at step k touches a width<k cell already written at its own step.
// trs(q+1,j)-trs(q,j) = kN-2-q (incremental col walk for the s00g scatter).
__global__ __launch_bounds__(kThreads) void eisner_dp(
    const float* __restrict__ vinfo,  // [B][N][N] fp32
    float* __restrict__ outS,         // [B][N][N][2][2] fp32 scores
    float* __restrict__ outBT,        // [B][N][N][2][2] fp32 backtrace (integer-valued)
    float* __restrict__ wsAll)        // [B][3][kTri]: s00g, s10g, btPacked(u32)
{
    extern __shared__ float sm[];
    float* s01s = sm;
    float* s01T = sm + kTri;
    float* s11s = sm + 2 * kTri;
    float* s11T = sm + 3 * kTri;

    const int tid = threadIdx.x;
    const int b = blockIdx.x;
    const float* v = vinfo + (size_t)b * kN * kN;
    float* wsB = wsAll + (size_t)b * 3 * kTri;
    float* s00g = wsB;
    float* s10g = wsB + kTri;
    uint32_t* wsBT = (uint32_t*)(wsB + 2 * kTri);

    // ---- DP over span width k ----
    for (int k = 1; k < kN; ++k) {
        const int R = kN - k;  // active rows

        if (k <= kSmallK) {
            // ======== small-k: one row per lane, serial scan, no reduction ========
            const int i = tid;
            if (i < R) {
                const int j = i + k;
                const float vL = v[j * kN + i];
                const float vR = v[i * kN + j];
                const int rbI = rowBase(i);
                const int cbJ = colBase(j);
                float best00 = -3.0e38f, best10 = -3.0e38f, best01 = -3.0e38f, best11 = -3.0e38f;
                int bi00 = 0, bi10 = 0, bi01 = 0, bi11 = 0x7FFFFFFF;
                int q = i;
                int tqj = rbI + k - 1;  // trs(i, j) == trs(q, j) at q=i
#pragma unroll 4
                for (int m = 0; m < k; ++m) {
                    const float a  = (m == 0)     ? 0.0f : s11s[rbI + m - 1];
                    const float bb = (m == k - 1) ? 0.0f : s01T[cbJ + q + 1];
                    const float base = a + bb;
                    const float p00v = fmaxf((base + vL) + kArcBonus, kNeg);
                    const float p10v = fmaxf((base + vR) + kArcBonus, kNeg);
                    if (m == 0) {
                        best00 = p00v; best10 = p10v;
                        best01 = (p00v > kThresh) ? p00v : kNeg;  // part00 seed, m=0
                    } else {
                        if (p00v > best00) { best00 = p00v; bi00 = m; }
                        if (p10v > best10) { best10 = p10v; bi10 = m; }
                        const float p01v = fmaxf(s01s[rbI + m - 1] + s00g[tqj], kNeg);
                        const float p11v = fmaxf(s10g[rbI + m - 1] + s11T[cbJ + q], kNeg);
                        if (p01v > best01) { best01 = p01v; bi01 = m; }
                        if (p11v > best11) { best11 = p11v; bi11 = m; }
                    }
                    tqj += (kN - 2) - q;  // -> trs(q+1, j)
                    ++q;
                }
                const float new10 = (best10 > kThresh) ? best10 : kNeg;
                if (new10 > best11) { best11 = new10; bi11 = k; }

                const int tIJ = rbI + k - 1;
                uint32_t p = 0;
                float v00 = kNeg, v01 = kNeg, v10 = kNeg, v11 = kNeg;
                if (best00 > kThresh) { v00 = best00; p |= (uint32_t)(i + bi00); }
                if (best01 > kThresh) { v01 = best01; p |= (uint32_t)(i + bi01) << 8; }
                if (best10 > kThresh) { v10 = best10; p |= (uint32_t)(i + bi10) << 16; }
                if (best11 > kThresh) { v11 = best11; p |= (uint32_t)(i + bi11) << 24; }
                s01s[tIJ] = v01; s01T[cbJ + i] = v01;
                s11s[tIJ] = v11; s11T[cbJ + i] = v11;
                s00g[tIJ] = v00; s10g[tIJ] = v10;
                wsBT[tIJ] = p;
            }
        } else {
            // ======== chunked groups + value butterfly + ballot argmax ========
            int P = 2, lp = 1;
            while (P < 64 && ((P << 1) * R) <= kThreads) { P <<= 1; ++lp; }
            int C = (k + P - 1) >> lp;  // chunk size
            C |= 1;                     // odd => across-lane stride odd => conflict-free
            const int l = tid & (P - 1);
            const int g = tid >> lp;
            const int laneId = tid & 63;
            const bool waveActive = (((tid & ~63) >> lp) < R);  // wave-uniform

            float loc00 = -3.0e38f, loc10 = -3.0e38f, loc01 = -3.0e38f, loc11 = -3.0e38f;
            int bi00 = 0x7FFFFFFF, bi10 = 0x7FFFFFFF, bi01 = 0x7FFFFFFF, bi11 = 0x7FFFFFFF;
            const int i = g;
            const int j = g + k;

            if (waveActive) {
                if (g < R) {
                    const int mlo = l * C;
                    const int mhi = (mlo + C < k) ? (mlo + C) : k;
                    if (mlo < mhi) {
                        const float vL = v[j * kN + i];
                        const float vR = v[i * kN + j];
                        const int rbI = rowBase(i);
                        const int cbJ = colBase(j);
                        int q = i + mlo;
                        int tqj = rowBase(q) + (j - q - 1);  // trs(q, j)
#pragma unroll 4
                        for (int m = mlo; m < mhi; ++m) {
                            const float a  = (m == 0)     ? 0.0f : s11s[rbI + m - 1];
                            const float bb = (m == k - 1) ? 0.0f : s01T[cbJ + q + 1];
                            const float base = a + bb;
                            const float p00v = fmaxf((base + vL) + kArcBonus, kNeg);
                            const float p10v = fmaxf((base + vR) + kArcBonus, kNeg);
                            if (m == 0) {
                                loc00 = p00v; bi00 = 0;
                                loc10 = p10v; bi10 = 0;
                                loc01 = (p00v > kThresh) ? p00v : kNeg;  // part00 seed
                                bi01 = 0;
                            } else {
                                if (p00v > loc00) { loc00 = p00v; bi00 = m; }
                                if (p10v > loc10) { loc10 = p10v; bi10 = m; }
                                const float p01v = fmaxf(s01s[rbI + m - 1] + s00g[tqj], kNeg);
                                const float p11v = fmaxf(s10g[rbI + m - 1] + s11T[cbJ + q], kNeg);
                                if (p01v > loc01) { loc01 = p01v; bi01 = m; }
                                if (p11v > loc11) { loc11 = p11v; bi11 = m; }
                            }
                            tqj += (kN - 2) - q;  // -> trs(q+1, j)
                            ++q;
                        }
                    }
                }
                // value-only butterfly (4 DS ops per stage)
                float g00 = loc00, g10 = loc10, g01 = loc01, g11 = loc11;
                for (int s = P >> 1; s >= 1; s >>= 1) {
                    g00 = fmaxf(g00, __shfl_xor(g00, s, 64));
                    g10 = fmaxf(g10, __shfl_xor(g10, s, 64));
                    g01 = fmaxf(g01, __shfl_xor(g01, s, 64));
                    g11 = fmaxf(g11, __shfl_xor(g11, s, 64));
                }
                // earliest-m via ballot (contiguous chunks => lane order == m order;
                // empty lanes hold -3e38 and can never equal the group max >= -9999)
                const int grpStart = laneId & ~(P - 1);
                const uint64_t gmask =
                    (P == 64) ? ~0ull : (((1ull << P) - 1ull) << grpStart);
                const uint64_t m0 = __ballot(loc00 == g00) & gmask;
                const uint64_t m1 = __ballot(loc10 == g10) & gmask;
                const uint64_t m2 = __ballot(loc01 == g01) & gmask;
                const uint64_t m3 = __ballot(loc11 == g11) & gmask;
                const int r00 = __shfl(bi00, __ffsll((unsigned long long)m0) - 1, 64);
                const int r10 = __shfl(bi10, __ffsll((unsigned long long)m1) - 1, 64);
                const int r01 = __shfl(bi01, __ffsll((unsigned long long)m2) - 1, 64);
                int r11 = __shfl(bi11, __ffsll((unsigned long long)m3) - 1, 64);

                if (g < R && l == 0) {
                    float b11 = g11;
                    const float new10 = (g10 > kThresh) ? g10 : kNeg;
                    if (new10 > b11) { b11 = new10; r11 = k; }

                    const int tIJ = rowBase(i) + k - 1;
                    const int cbJ = colBase(j);
                    uint32_t p = 0;
                    float v00 = kNeg, v01 = kNeg, v10 = kNeg, v11 = kNeg;
                    if (g00 > kThresh) { v00 = g00; p |= (uint32_t)(i + r00); }
                    if (g01 > kThresh) { v01 = g01; p |= (uint32_t)(i + r01) << 8; }
                    if (g10 > kThresh) { v10 = g10; p |= (uint32_t)(i + r10) << 16; }
                    if (b11 > kThresh) { v11 = b11; p |= (uint32_t)(i + r11) << 24; }
                    s01s[tIJ] = v01; s01T[cbJ + i] = v01;
                    s11s[tIJ] = v11; s11T[cbJ + i] = v11;
                    s00g[tIJ] = v00; s10g[tIJ] = v10;
                    wsBT[tIJ] = p;
                }
            }
        }
        // Barrier orders this step's LDS + scratch writes before next step's
        // reads (vmcnt/lgkmcnt drained before s_barrier).
        __syncthreads();
    }

    // ---- epilogue: emit full [N][N][2][2] scores + backtrace, coalesced ----
    float4* gS4 = (float4*)(outS + (size_t)b * kN * kN * 4);
    float4* gB4 = (float4*)(outBT + (size_t)b * kN * kN * 4);
    const float4 negq = make_float4(kNeg, kNeg, kNeg, kNeg);
    const float4 zeroq = make_float4(0.f, 0.f, 0.f, 0.f);
    for (int c = tid; c < kN * kN; c += kThreads) {
        const int i = c >> 7, j = c & (kN - 1);
        if (i < j) {
            const int t = rowBase(i) + (j - i - 1);
            gS4[c] = make_float4(s00g[t], s01s[t], s10g[t], s11s[t]);
            const uint32_t p = wsBT[t];
            gB4[c] = make_float4((float)(p & 255u), (float)((p >> 8) & 255u),
                                 (float)((p >> 16) & 255u), (float)(p >> 24));
        } else if (i == j) {
            gS4[c] = zeroq;
            gB4[c] = zeroq;
        } else {
            gS4[c] = negq;
            gB4[c] = zeroq;
        }
    }
}

extern "C" void kernel_launch(void* const* d_in, const int* in_sizes, int n_in,
                              void* d_out, int out_size, void* d_ws, size_t ws_size,
                              hipStream_t stream) {
    (void)n_in; (void)out_size; (void)ws_size;
    const float* vinfo = (const float*)d_in[0];  // fp32 [B][N][N]
    const int B = in_sizes[1];                   // b_buffer_size has B elements
    float* outS = (float*)d_out;
    float* outBT = outS + (size_t)B * kN * kN * 4;
    float* wsAll = (float*)d_ws;                 // needs B*3*kTri*4 = ~6.25 MB

    // Opt in to >64KB dynamic LDS (host-side, idempotent; proven in r8).
    hipFuncSetAttribute(reinterpret_cast<const void*>(eisner_dp),
                        hipFuncAttributeMaxDynamicSharedMemorySize, kDynLds);

    eisner_dp<<<dim3(B), dim3(kThreads), kDynLds, stream>>>(vinfo, outS, outBT, wsAll);
}

// Round 10
// 376.187 us; speedup vs baseline: 1.2672x; 1.2672x over previous
//
#include <hip/hip_runtime.h>
#include <stdint.h>

static constexpr int kN = 128;
static constexpr int kTri = (kN * (kN - 1)) / 2;  // strict upper triangle: 8128 cells
static constexpr int kThreads = 1024;
static constexpr int kSerialK = 48;  // k <= this: one row per lane, no reduction
static constexpr float kNeg = -9999.0f;
static constexpr float kThresh = -9000.0f;
static constexpr float kArcBonus = 5.0f;
// LDS: C3 = col-major triples {s00,s11,s01} (3*kTri floats) + R1 = row-major s10 (kTri)
static constexpr int kDynLds = 4 * kTri * (int)sizeof(float);  // 130,048 B (proven r8)

__device__ __forceinline__ int rowBase(int i) { return (i * (2 * kN - 1 - i)) / 2; }
__device__ __forceinline__ int colBase(int j) { return (j * (j - 1)) / 2; }

// Butterfly-max stages on the VALU pipe via DPP (groups are aligned pow2 blocks).
template <int CTRL>
__device__ __forceinline__ float dppMax(float x) {
    const int y = __builtin_amdgcn_update_dpp(__float_as_int(x), __float_as_int(x),
                                              CTRL, 0xF, 0xF, true);
    return fmaxf(x, __int_as_float(y));
}
__device__ __forceinline__ float swzMax16(float x) {  // xor-16 within 32 lanes
    const int y = __builtin_amdgcn_ds_swizzle(__float_as_int(x), 0x401F);
    return fmaxf(x, __int_as_float(y));
}

// Scan splits m in [mlo, mhi) for cell (i, j=i+k). Call only when mlo < mhi.
// Reads per iter: contiguous triple (carried), adjacent diag pair, R1 scalar.
__device__ __forceinline__ void scanChunk(const float* __restrict__ C3,
                                          const float* __restrict__ R1,
                                          int i, int j, int k, int mlo, int mhi,
                                          float vL, float vR,
                                          float& v00, float& v10, float& v01, float& v11,
                                          int& i00, int& i10, int& i01, int& i11) {
    const int cbJ = colBase(j);
    const int rbI = rowBase(i);
    int mstart = mlo;
    int q = i + ((mlo == 0) ? 1 : mlo);
    const int t3 = 3 * (cbJ + q);
    float c00 = C3[t3 + 0];  // s00[q][j]   (garbage if mlo==0 && k==1: unused)
    float c11 = C3[t3 + 1];  // s11[q][j]
    float c01 = C3[t3 + 2];  // s01[q][j]
    if (mlo == 0) {
        // m = 0: a = 0; bb = (k==1)?0:s01[i+1][j] (== c01, cur preloaded at q=i+1)
        const float bb0 = (k == 1) ? 0.0f : c01;
        const float p00 = fmaxf((bb0 + vL) + kArcBonus, kNeg);
        const float p10 = fmaxf((bb0 + vR) + kArcBonus, kNeg);
        v00 = p00; i00 = 0;
        v10 = p10; i10 = 0;
        v01 = (p00 > kThresh) ? p00 : kNeg; i01 = 0;  // part00 seed
        mstart = 1;
    }
    int t3n = 3 * (cbJ + q + 1);     // triple(q+1)
    int dq = 3 * q;                  // colBase(q+1)-colBase(q) = q  (x3 dwords)
    int dA = 3 * (colBase(q) + i);   // diag cell (i,q)
    int rA = rbI + mstart - 1;
#pragma unroll 4
    for (int m = mstart; m < mhi; ++m) {
        const float n00 = C3[t3n + 0];
        const float n11 = C3[t3n + 1];
        const float n01 = C3[t3n + 2];
        const float d11 = C3[dA + 1];  // s11[i][q]
        const float d01 = C3[dA + 2];  // s01[i][q]
        const float r10 = R1[rA];      // s10[i][q]
        const float bb = (m == k - 1) ? 0.0f : n01;  // s01[q+1][j]
        const float base = d11 + bb;
        const float p00 = fmaxf((base + vL) + kArcBonus, kNeg);
        const float p10 = fmaxf((base + vR) + kArcBonus, kNeg);
        const float p01 = fmaxf(d01 + c00, kNeg);    // s01[i][q] + s00[q][j]
        const float p11 = fmaxf(r10 + c11, kNeg);    // s10[i][q] + s11[q][j]
        if (p00 > v00) { v00 = p00; i00 = m; }       // strict > keeps earliest m
        if (p10 > v10) { v10 = p10; i10 = m; }
        if (p01 > v01) { v01 = p01; i01 = m; }
        if (p11 > v11) { v11 = p11; i11 = m; }
        c00 = n00; c11 = n11;
        t3n += 3;
        dA += dq; dq += 3;
        ++rA;
    }
}

__device__ __forceinline__ void writeCell(float* __restrict__ C3, float* __restrict__ R1,
                                          uint32_t* __restrict__ wsBT,
                                          int i, int j, int k,
                                          float v00, float v10, float v01, float v11,
                                          int i00, int i10, int i01, int i11) {
    const float new10 = (v10 > kThresh) ? v10 : kNeg;
    if (new10 > v11) { v11 = new10; i11 = k; }  // q=j candidate; strict > keeps earlier q
    float w00 = kNeg, w10 = kNeg, w01 = kNeg, w11 = kNeg;
    uint32_t p = 0;
    if (v00 > kThresh) { w00 = v00; p |= (uint32_t)(i + i00); }
    if (v01 > kThresh) { w01 = v01; p |= (uint32_t)(i + i01) << 8; }
    if (v10 > kThresh) { w10 = v10; p |= (uint32_t)(i + i10) << 16; }
    if (v11 > kThresh) { w11 = v11; p |= (uint32_t)(i + i11) << 24; }
    const int cIJ = colBase(j) + i;
    const int tIJ = rowBase(i) + k - 1;
    C3[3 * cIJ + 0] = w00;
    C3[3 * cIJ + 1] = w11;
    C3[3 * cIJ + 2] = w01;
    R1[tIJ] = w10;
    wsBT[tIJ] = p;  // single global store per cell
}

__global__ __launch_bounds__(kThreads) void eisner_dp(
    const float* __restrict__ vinfo,  // [B][N][N] fp32
    float* __restrict__ outS,         // [B][N][N][2][2] fp32 scores
    float* __restrict__ outBT,        // [B][N][N][2][2] fp32 backtrace (integer-valued)
    uint32_t* __restrict__ btPacked)  // [B][kTri] packed backtrace bytes (d_ws)
{
    extern __shared__ float sm[];
    float* C3 = sm;
    float* R1 = sm + 3 * kTri;

    const int tid = threadIdx.x;
    const int b = blockIdx.x;
    const float* v = vinfo + (size_t)b * kN * kN;
    uint32_t* wsBT = btPacked + (size_t)b * kTri;

    // No LDS init needed: at step k, every read touches a width<k cell that was
    // written unconditionally at its own step; k=1 reads nothing.

    for (int k = 1; k < kN; ++k) {
        const int R = kN - k;  // active rows

        if (k <= kSerialK) {
            // ---- serial: one row per lane, zero reduction overhead ----
            const int i = tid;
            if (i < R) {
                const int j = i + k;
                const float vL = v[j * kN + i];
                const float vR = v[i * kN + j];
                float v00 = -3.0e38f, v10 = -3.0e38f, v01 = -3.0e38f, v11 = -3.0e38f;
                int i00 = 0, i10 = 0, i01 = 0, i11 = 0x7FFFFFFF;
                scanChunk(C3, R1, i, j, k, 0, k, vL, vR,
                          v00, v10, v01, v11, i00, i10, i01, i11);
                writeCell(C3, R1, wsBT, i, j, k, v00, v10, v01, v11, i00, i10, i01, i11);
            }
        } else {
            // ---- chunked groups + DPP butterfly + ballot argmax ----
            int P = 2, lp = 1;
            while (P < 64 && ((P << 1) * R) <= kThreads) { P <<= 1; ++lp; }
            int C = (k + P - 1) >> lp;
            C |= 1;  // odd chunk => odd across-lane strides => conflict-free walks
            const int l = tid & (P - 1);
            const int g = tid >> lp;
            const int laneId = tid & 63;
            const bool waveActive = (((tid & ~63) >> lp) < R);  // wave-uniform

            if (waveActive) {
                float v00 = -3.0e38f, v10 = -3.0e38f, v01 = -3.0e38f, v11 = -3.0e38f;
                int i00 = 0x7FFFFFFF, i10 = 0x7FFFFFFF, i01 = 0x7FFFFFFF, i11 = 0x7FFFFFFF;
                const int i = g;
                const int j = g + k;
                const int mlo = l * C;
                const int mhi = (mlo + C < k) ? (mlo + C) : k;
                if (g < R && mlo < mhi) {
                    const float vL = v[j * kN + i];
                    const float vR = v[i * kN + j];
                    scanChunk(C3, R1, i, j, k, mlo, mhi, vL, vR,
                              v00, v10, v01, v11, i00, i10, i01, i11);
                }
                // group max: k>48 => P>=8, first three stages unconditional (VALU)
                float g00 = dppMax<0x141>(dppMax<0x4E>(dppMax<0xB1>(v00)));
                float g10 = dppMax<0x141>(dppMax<0x4E>(dppMax<0xB1>(v10)));
                float g01 = dppMax<0x141>(dppMax<0x4E>(dppMax<0xB1>(v01)));
                float g11 = dppMax<0x141>(dppMax<0x4E>(dppMax<0xB1>(v11)));
                if (P >= 16) {
                    g00 = dppMax<0x140>(g00); g10 = dppMax<0x140>(g10);
                    g01 = dppMax<0x140>(g01); g11 = dppMax<0x140>(g11);
                }
                if (P >= 32) {
                    g00 = swzMax16(g00); g10 = swzMax16(g10);
                    g01 = swzMax16(g01); g11 = swzMax16(g11);
                }
                if (P == 64) {
                    g00 = fmaxf(g00, __shfl_xor(g00, 32, 64));
                    g10 = fmaxf(g10, __shfl_xor(g10, 32, 64));
                    g01 = fmaxf(g01, __shfl_xor(g01, 32, 64));
                    g11 = fmaxf(g11, __shfl_xor(g11, 32, 64));
                }
                // earliest-m via ballot (contiguous chunks => lane order == m order;
                // empty lanes hold -3e38, can never equal group max >= -9999)
                const int grpStart = laneId & ~(P - 1);
                const uint64_t gmask =
                    (P == 64) ? ~0ull : (((1ull << P) - 1ull) << grpStart);
                const uint64_t m0 = __ballot(v00 == g00) & gmask;
                const uint64_t m1 = __ballot(v10 == g10) & gmask;
                const uint64_t m2 = __ballot(v01 == g01) & gmask;
                const uint64_t m3 = __ballot(v11 == g11) & gmask;
                const int r00 = __shfl(i00, __ffsll((unsigned long long)m0) - 1, 64);
                const int r10 = __shfl(i10, __ffsll((unsigned long long)m1) - 1, 64);
                const int r01 = __shfl(i01, __ffsll((unsigned long long)m2) - 1, 64);
                const int r11 = __shfl(i11, __ffsll((unsigned long long)m3) - 1, 64);

                if (g < R && l == 0) {
                    writeCell(C3, R1, wsBT, i, j, k, g00, g10, g01, g11, r00, r10, r01, r11);
                }
            }
        }
        // Barrier orders this step's LDS writes (and the lone BT store) before
        // next step's reads.
        __syncthreads();
    }

    // ---- epilogue: emit full [N][N][2][2] scores + backtrace, coalesced ----
    float4* gS4 = (float4*)(outS + (size_t)b * kN * kN * 4);
    float4* gB4 = (float4*)(outBT + (size_t)b * kN * kN * 4);
    const float4 negq = make_float4(kNeg, kNeg, kNeg, kNeg);
    const float4 zeroq = make_float4(0.f, 0.f, 0.f, 0.f);
    for (int c = tid; c < kN * kN; c += kThreads) {
        const int i = c >> 7, j = c & (kN - 1);
        if (i < j) {
            const int ct = colBase(j) + i;
            const int rt = rowBase(i) + (j - i - 1);
            gS4[c] = make_float4(C3[3 * ct], C3[3 * ct + 2], R1[rt], C3[3 * ct + 1]);
            const uint32_t p = wsBT[rt];
            gB4[c] = make_float4((float)(p & 255u), (float)((p >> 8) & 255u),
                                 (float)((p >> 16) & 255u), (float)(p >> 24));
        } else if (i == j) {
            gS4[c] = zeroq;
            gB4[c] = zeroq;
        } else {
            gS4[c] = negq;
            gB4[c] = zeroq;
        }
    }
}

extern "C" void kernel_launch(void* const* d_in, const int* in_sizes, int n_in,
                              void* d_out, int out_size, void* d_ws, size_t ws_size,
                              hipStream_t stream) {
    (void)n_in; (void)out_size; (void)ws_size;
    const float* vinfo = (const float*)d_in[0];  // fp32 [B][N][N]
    const int B = in_sizes[1];                   // b_buffer_size has B elements
    float* outS = (float*)d_out;
    float* outBT = outS + (size_t)B * kN * kN * 4;
    uint32_t* btPacked = (uint32_t*)d_ws;        // needs B*kTri*4 = ~2.1 MB

    // Opt in to >64KB dynamic LDS (host-side, idempotent; proven in r8).
    hipFuncSetAttribute(reinterpret_cast<const void*>(eisner_dp),
                        hipFuncAttributeMaxDynamicSharedMemorySize, kDynLds);

    eisner_dp<<<dim3(B), dim3(kThreads), kDynLds, stream>>>(vinfo, outS, outBT, btPacked);
}

// Round 11
// 373.928 us; speedup vs baseline: 1.2749x; 1.0060x over previous
//
#include <hip/hip_runtime.h>
#include <stdint.h>

static constexpr int kN = 128;
static constexpr int kTri = (kN * (kN - 1)) / 2;   // 8128 (BT scratch indexing)
static constexpr int kTriD = (kN * (kN + 1)) / 2;  // 8256 cells incl. diagonal
static constexpr int kThreads = 1024;
static constexpr int kSerialK = 48;  // k <= this: one row per lane, no reduction
static constexpr float kNeg = -9999.0f;
static constexpr float kThresh = -9000.0f;
static constexpr float kArcBonus = 5.0f;
static constexpr int kDynLds = kTriD * 16;  // 132,096 B (one float4 quad per cell)

__device__ __forceinline__ int rowBase(int i) { return (i * (2 * kN - 1 - i)) / 2; }
__device__ __forceinline__ int colBaseD(int c) { return (c * (c + 1)) / 2; }  // cells (r<=c, c)

// Butterfly-max stages on the VALU pipe via DPP (groups are aligned pow2 blocks).
template <int CTRL>
__device__ __forceinline__ float dppMax(float x) {
    const int y = __builtin_amdgcn_update_dpp(__float_as_int(x), __float_as_int(x),
                                              CTRL, 0xF, 0xF, true);
    return fmaxf(x, __int_as_float(y));
}
__device__ __forceinline__ float swzMax16(float x) {  // xor-16 within 32 lanes
    const int y = __builtin_amdgcn_ds_swizzle(__float_as_int(x), 0x401F);
    return fmaxf(x, __int_as_float(y));
}

// Quad per cell: {x=s00, y=s11, z=s01, w=s10}, col-major incl. diagonal (diag = 0).
// Per iter: 2 x ds_read_b128 — quad(q+1, j) [carried] and quad(i, q).
// Diagonal-in-layout makes the m==0 / m==k-1 boundary values (0) natural reads.
__device__ __forceinline__ void scanChunk(const float4* __restrict__ Q4,
                                          int i, int j, int k, int mlo, int mhi,
                                          float vL, float vR,
                                          float& v00, float& v10, float& v01, float& v11,
                                          int& i00, int& i10, int& i01, int& i11) {
    const int qjb = colBaseD(j);  // + r => cell (r, j)
    int q, mstart;
    float4 cur;
    if (mlo == 0) {
        q = i + 1;
        cur = Q4[qjb + q];  // quad(i+1, j); diagonal zeros when k==1
        const float p00 = fmaxf((cur.z + vL) + kArcBonus, kNeg);
        const float p10 = fmaxf((cur.z + vR) + kArcBonus, kNeg);
        v00 = p00; i00 = 0;
        v10 = p10; i10 = 0;
        v01 = (p00 > kThresh) ? p00 : kNeg; i01 = 0;  // part00 seed
        mstart = 1;
    } else {
        q = i + mlo;
        cur = Q4[qjb + q];
        mstart = mlo;
    }
    int dA = colBaseD(q) + i;  // cell (i, q)
    int dInc = q + 1;          // colBaseD(q+1) - colBaseD(q)
#pragma unroll 4
    for (int m = mstart; m < mhi; ++m) {
        const float4 nxt = Q4[qjb + q + 1];  // quad(q+1, j); diag zeros at m==k-1
        const float4 diq = Q4[dA];           // quad(i, q)
        const float base = diq.y + nxt.z;    // s11[i][q] + s01[q+1][j]
        const float p00 = fmaxf((base + vL) + kArcBonus, kNeg);
        const float p10 = fmaxf((base + vR) + kArcBonus, kNeg);
        const float p01 = fmaxf(diq.z + cur.x, kNeg);  // s01[i][q] + s00[q][j]
        const float p11 = fmaxf(diq.w + cur.y, kNeg);  // s10[i][q] + s11[q][j]
        if (p00 > v00) { v00 = p00; i00 = m; }         // strict > keeps earliest m
        if (p10 > v10) { v10 = p10; i10 = m; }
        if (p01 > v01) { v01 = p01; i01 = m; }
        if (p11 > v11) { v11 = p11; i11 = m; }
        cur = nxt;
        dA += dInc; ++dInc;
        ++q;
    }
}

__device__ __forceinline__ void writeCell(float4* __restrict__ Q4,
                                          uint32_t* __restrict__ wsBT,
                                          int i, int j, int k,
                                          float v00, float v10, float v01, float v11,
                                          int i00, int i10, int i01, int i11) {
    const float new10 = (v10 > kThresh) ? v10 : kNeg;
    if (new10 > v11) { v11 = new10; i11 = k; }  // q=j candidate; strict > keeps earlier q
    float4 w = make_float4(kNeg, kNeg, kNeg, kNeg);
    uint32_t p = 0;
    if (v00 > kThresh) { w.x = v00; p |= (uint32_t)(i + i00); }
    if (v01 > kThresh) { w.z = v01; p |= (uint32_t)(i + i01) << 8; }
    if (v10 > kThresh) { w.w = v10; p |= (uint32_t)(i + i10) << 16; }
    if (v11 > kThresh) { w.y = v11; p |= (uint32_t)(i + i11) << 24; }
    Q4[colBaseD(j) + i] = w;          // one ds_write_b128
    wsBT[rowBase(i) + k - 1] = p;     // single global store per cell
}

__global__ __launch_bounds__(kThreads) void eisner_dp(
    const float* __restrict__ vinfo,  // [B][N][N] fp32
    float* __restrict__ outS,         // [B][N][N][2][2] fp32 scores
    float* __restrict__ outBT,        // [B][N][N][2][2] fp32 backtrace (integer-valued)
    uint32_t* __restrict__ btPacked)  // [B][kTri] packed backtrace bytes (d_ws)
{
    extern __shared__ float4 Q4[];

    const int tid = threadIdx.x;
    const int b = blockIdx.x;
    const float* v = vinfo + (size_t)b * kN * kN;
    uint32_t* wsBT = btPacked + (size_t)b * kTri;

    // Diagonal quads = 0 (S[i][i][*][*] = 0). Off-diagonal cells need no init:
    // at step k every read touches a width<k cell written unconditionally.
    const float4 zeroq = make_float4(0.f, 0.f, 0.f, 0.f);
    if (tid < kN) Q4[colBaseD(tid) + tid] = zeroq;
    __syncthreads();

    for (int k = 1; k < kN; ++k) {
        const int R = kN - k;  // active rows

        if (k <= kSerialK) {
            // ---- serial: one row per lane, zero reduction overhead ----
            const int i = tid;
            if (i < R) {
                const int j = i + k;
                const float vL = v[j * kN + i];
                const float vR = v[i * kN + j];
                float v00 = -3.0e38f, v10 = -3.0e38f, v01 = -3.0e38f, v11 = -3.0e38f;
                int i00 = 0, i10 = 0, i01 = 0, i11 = 0x7FFFFFFF;
                scanChunk(Q4, i, j, k, 0, k, vL, vR,
                          v00, v10, v01, v11, i00, i10, i01, i11);
                writeCell(Q4, wsBT, i, j, k, v00, v10, v01, v11, i00, i10, i01, i11);
            }
        } else {
            // ---- chunked groups + DPP butterfly + ballot argmax ----
            int P = 2, lp = 1;
            while (P < 64 && ((P << 1) * R) <= kThreads) { P <<= 1; ++lp; }
            int C = (k + P - 1) >> lp;
            C |= 1;  // odd chunk => odd quad strides within groups
            const int l = tid & (P - 1);
            const int g = tid >> lp;
            const int laneId = tid & 63;
            const bool waveActive = (((tid & ~63) >> lp) < R);  // wave-uniform

            if (waveActive) {
                float v00 = -3.0e38f, v10 = -3.0e38f, v01 = -3.0e38f, v11 = -3.0e38f;
                int i00 = 0x7FFFFFFF, i10 = 0x7FFFFFFF, i01 = 0x7FFFFFFF, i11 = 0x7FFFFFFF;
                const int i = g;
                const int j = g + k;
                const int mlo = l * C;
                const int mhi = (mlo + C < k) ? (mlo + C) : k;
                if (g < R && mlo < mhi) {
                    const float vL = v[j * kN + i];
                    const float vR = v[i * kN + j];
                    scanChunk(Q4, i, j, k, mlo, mhi, vL, vR,
                              v00, v10, v01, v11, i00, i10, i01, i11);
                }
                // group max: k>48 => P>=8, first three stages unconditional (VALU)
                float g00 = dppMax<0x141>(dppMax<0x4E>(dppMax<0xB1>(v00)));
                float g10 = dppMax<0x141>(dppMax<0x4E>(dppMax<0xB1>(v10)));
                float g01 = dppMax<0x141>(dppMax<0x4E>(dppMax<0xB1>(v01)));
                float g11 = dppMax<0x141>(dppMax<0x4E>(dppMax<0xB1>(v11)));
                if (P >= 16) {
                    g00 = dppMax<0x140>(g00); g10 = dppMax<0x140>(g10);
                    g01 = dppMax<0x140>(g01); g11 = dppMax<0x140>(g11);
                }
                if (P >= 32) {
                    g00 = swzMax16(g00); g10 = swzMax16(g10);
                    g01 = swzMax16(g01); g11 = swzMax16(g11);
                }
                if (P == 64) {
                    g00 = fmaxf(g00, __shfl_xor(g00, 32, 64));
                    g10 = fmaxf(g10, __shfl_xor(g10, 32, 64));
                    g01 = fmaxf(g01, __shfl_xor(g01, 32, 64));
                    g11 = fmaxf(g11, __shfl_xor(g11, 32, 64));
                }
                // earliest-m via ballot (contiguous chunks => lane order == m order;
                // empty lanes hold -3e38, can never equal group max >= -9999)
                const int grpStart = laneId & ~(P - 1);
                const uint64_t gmask =
                    (P == 64) ? ~0ull : (((1ull << P) - 1ull) << grpStart);
                const uint64_t m0 = __ballot(v00 == g00) & gmask;
                const uint64_t m1 = __ballot(v10 == g10) & gmask;
                const uint64_t m2 = __ballot(v01 == g01) & gmask;
                const uint64_t m3 = __ballot(v11 == g11) & gmask;
                const int r00 = __shfl(i00, __ffsll((unsigned long long)m0) - 1, 64);
                const int r10 = __shfl(i10, __ffsll((unsigned long long)m1) - 1, 64);
                const int r01 = __shfl(i01, __ffsll((unsigned long long)m2) - 1, 64);
                const int r11 = __shfl(i11, __ffsll((unsigned long long)m3) - 1, 64);

                if (g < R && l == 0) {
                    writeCell(Q4, wsBT, i, j, k, g00, g10, g01, g11, r00, r10, r01, r11);
                }
            }
        }
        // Barrier orders this step's LDS writes (and the lone BT store) before
        // next step's reads.
        __syncthreads();
    }

    // ---- epilogue: emit full [N][N][2][2] scores + backtrace, coalesced ----
    float4* gS4 = (float4*)(outS + (size_t)b * kN * kN * 4);
    float4* gB4 = (float4*)(outBT + (size_t)b * kN * kN * 4);
    const float4 negq = make_float4(kNeg, kNeg, kNeg, kNeg);
    for (int c = tid; c < kN * kN; c += kThreads) {
        const int i = c >> 7, j = c & (kN - 1);
        if (i < j) {
            const float4 q = Q4[colBaseD(j) + i];
            gS4[c] = make_float4(q.x, q.z, q.w, q.y);  // {s00, s01, s10, s11}
            const uint32_t p = wsBT[rowBase(i) + (j - i - 1)];
            gB4[c] = make_float4((float)(p & 255u), (float)((p >> 8) & 255u),
                                 (float)((p >> 16) & 255u), (float)(p >> 24));
        } else if (i == j) {
            gS4[c] = zeroq;
            gB4[c] = zeroq;
        } else {
            gS4[c] = negq;
            gB4[c] = zeroq;
        }
    }
}

extern "C" void kernel_launch(void* const* d_in, const int* in_sizes, int n_in,
                              void* d_out, int out_size, void* d_ws, size_t ws_size,
                              hipStream_t stream) {
    (void)n_in; (void)out_size; (void)ws_size;
    const float* vinfo = (const float*)d_in[0];  // fp32 [B][N][N]
    const int B = in_sizes[1];                   // b_buffer_size has B elements
    float* outS = (float*)d_out;
    float* outBT = outS + (size_t)B * kN * kN * 4;
    uint32_t* btPacked = (uint32_t*)d_ws;        // needs B*kTri*4 = ~2.1 MB

    // Opt in to >64KB dynamic LDS (132,096 B; 130,048 proven in r8; 160 KiB/CU cap).
    hipFuncSetAttribute(reinterpret_cast<const void*>(eisner_dp),
                        hipFuncAttributeMaxDynamicSharedMemorySize, kDynLds);

    eisner_dp<<<dim3(B), dim3(kThreads), kDynLds, stream>>>(vinfo, outS, outBT, btPacked);
}

// Round 12
// 358.474 us; speedup vs baseline: 1.3298x; 1.0431x over previous
//
#include <hip/hip_runtime.h>
#include <stdint.h>

static constexpr int kN = 128;
static constexpr int kTri = (kN * (kN - 1)) / 2;   // 8128 (BT scratch indexing)
static constexpr int kTriD = (kN * (kN + 1)) / 2;  // 8256 cells incl. diagonal
static constexpr int kThreads = 1024;
static constexpr int kSerialK = 16;  // k <= this: one row per lane, no reduction
static constexpr float kNeg = -9999.0f;
static constexpr float kThresh = -9000.0f;
static constexpr float kArcBonus = 5.0f;
static constexpr int kDynLds = kTriD * 16;  // 132,096 B (one float4 quad per cell)

__device__ __forceinline__ int rowBase(int i) { return (i * (2 * kN - 1 - i)) / 2; }
__device__ __forceinline__ int colBaseD(int c) { return (c * (c + 1)) / 2; }  // cells (r<=c, c)

// LDS-only workgroup barrier: orders LDS ops without draining vmcnt, so the
// per-step wsBT global store (read only in the epilogue) stays in flight.
__device__ __forceinline__ void ldsBarrier() {
    asm volatile("s_waitcnt lgkmcnt(0)\n\ts_barrier" ::: "memory");
}

template <int CTRL>
__device__ __forceinline__ float dppMax(float x) {
    const int y = __builtin_amdgcn_update_dpp(__float_as_int(x), __float_as_int(x),
                                              CTRL, 0xF, 0xF, true);
    return fmaxf(x, __int_as_float(y));
}
__device__ __forceinline__ float swzMax16(float x) {  // xor-16 within 32 lanes
    const int y = __builtin_amdgcn_ds_swizzle(__float_as_int(x), 0x401F);
    return fmaxf(x, __int_as_float(y));
}

// Thread's (i, j, active, P, lp) for step k. Uniform scalar math.
__device__ __forceinline__ void mapK(int k, int tid, int& i, int& j, bool& act,
                                     int& P, int& lp) {
    const int R = kN - k;
    if (k <= kSerialK) {
        P = 1; lp = 0; i = tid; j = tid + k; act = (tid < R);
    } else {
        P = 2; lp = 1;
        while (P < 64 && ((P << 1) * R) <= kThreads) { P <<= 1; ++lp; }
        i = tid >> lp; j = i + k; act = (i < R);
    }
}

// Quad per cell: {x=s00, y=s11, z=s01, w=s10}, col-major incl. diagonal (diag=0).
// Per iter: 2 x ds_read_b128 — quad(q+1, j) [carried] and quad(i, q).
// No per-candidate kNeg clamp: max distributes over clamp for values, and the
// clamp can only change the argmax among candidates <= -9999, which implies a
// final value <= THRESH => no write => unobservable. part00/new10 selects kept.
__device__ __forceinline__ void scanChunk(const float4* __restrict__ Q4,
                                          int i, int j, int k, int mlo, int mhi,
                                          float vL, float vR,
                                          float& v00, float& v10, float& v01, float& v11,
                                          int& i00, int& i10, int& i01, int& i11) {
    const int qjb = colBaseD(j);  // + r => cell (r, j)
    int q, mstart;
    float4 cur;
    if (mlo == 0) {
        q = i + 1;
        cur = Q4[qjb + q];  // quad(i+1, j); diagonal zeros when k==1
        const float p00 = (cur.z + vL) + kArcBonus;
        const float p10 = (cur.z + vR) + kArcBonus;
        v00 = p00; i00 = 0;
        v10 = p10; i10 = 0;
        v01 = (p00 > kThresh) ? p00 : kNeg; i01 = 0;  // part00 seed
        mstart = 1;
    } else {
        q = i + mlo;
        cur = Q4[qjb + q];
        mstart = mlo;
    }
    int dA = colBaseD(q) + i;  // cell (i, q)
    int dInc = q + 1;          // colBaseD(q+1) - colBaseD(q)
#pragma unroll 4
    for (int m = mstart; m < mhi; ++m) {
        const float4 nxt = Q4[qjb + q + 1];  // quad(q+1, j); diag zeros at m==k-1
        const float4 diq = Q4[dA];           // quad(i, q)
        const float base = diq.y + nxt.z;    // s11[i][q] + s01[q+1][j]
        const float p00 = (base + vL) + kArcBonus;
        const float p10 = (base + vR) + kArcBonus;
        const float p01 = diq.z + cur.x;     // s01[i][q] + s00[q][j]
        const float p11 = diq.w + cur.y;     // s10[i][q] + s11[q][j]
        if (p00 > v00) { v00 = p00; i00 = m; }  // strict > keeps earliest m
        if (p10 > v10) { v10 = p10; i10 = m; }
        if (p01 > v01) { v01 = p01; i01 = m; }
        if (p11 > v11) { v11 = p11; i11 = m; }
        cur = nxt;
        dA += dInc; ++dInc;
        ++q;
    }
}

__device__ __forceinline__ void writeCell(float4* __restrict__ Q4,
                                          uint32_t* __restrict__ wsBT,
                                          int i, int j, int k,
                                          float v00, float v10, float v01, float v11,
                                          int i00, int i10, int i01, int i11) {
    const float new10 = (v10 > kThresh) ? v10 : kNeg;
    if (new10 > v11) { v11 = new10; i11 = k; }  // q=j candidate; strict > keeps earlier q
    float4 w = make_float4(kNeg, kNeg, kNeg, kNeg);
    uint32_t p = 0;
    if (v00 > kThresh) { w.x = v00; p |= (uint32_t)(i + i00); }
    if (v01 > kThresh) { w.z = v01; p |= (uint32_t)(i + i01) << 8; }
    if (v10 > kThresh) { w.w = v10; p |= (uint32_t)(i + i10) << 16; }
    if (v11 > kThresh) { w.y = v11; p |= (uint32_t)(i + i11) << 24; }
    Q4[colBaseD(j) + i] = w;          // one ds_write_b128
    wsBT[rowBase(i) + k - 1] = p;     // lone global store; NOT drained per step
}

__global__ __launch_bounds__(kThreads) void eisner_dp(
    const float* __restrict__ vinfo,  // [B][N][N] fp32
    float* __restrict__ outS,         // [B][N][N][2][2] fp32 scores
    float* __restrict__ outBT,        // [B][N][N][2][2] fp32 backtrace (integer-valued)
    uint32_t* __restrict__ btPacked)  // [B][kTri] packed backtrace bytes (d_ws)
{
    extern __shared__ float4 Q4[];

    const int tid = threadIdx.x;
    const int b = blockIdx.x;
    const float* v = vinfo + (size_t)b * kN * kN;
    uint32_t* wsBT = btPacked + (size_t)b * kTri;

    // Diagonal quads = 0 (S[i][i][*][*] = 0). Off-diagonal cells need no init.
    const float4 zeroq = make_float4(0.f, 0.f, 0.f, 0.f);
    if (tid < kN) Q4[colBaseD(tid) + tid] = zeroq;

    // Prefetch step-1 mapping + vL/vR.
    int ci, cj; bool cact; int cP, clp;
    mapK(1, tid, ci, cj, cact, cP, clp);
    float vL = cact ? v[cj * kN + ci] : 0.f;
    float vR = cact ? v[ci * kN + cj] : 0.f;
    __syncthreads();

    for (int k = 1; k < kN; ++k) {
        const int R = kN - k;
        const int laneId = tid & 63;

        float v00 = -3.0e38f, v10 = -3.0e38f, v01 = -3.0e38f, v11 = -3.0e38f;
        int i00 = 0, i10 = 0, i01 = 0, i11 = 0x7FFFFFFF;
        const int i = ci, j = cj;
        const bool act = cact;
        const int P = cP, lp = clp;

        if (P == 1) {
            if (act) {
                scanChunk(Q4, i, j, k, 0, k, vL, vR,
                          v00, v10, v01, v11, i00, i10, i01, i11);
            }
        } else {
            int C = (k + P - 1) >> lp;
            C |= 1;  // odd chunk => odd quad strides within groups
            const int l = tid & (P - 1);
            const int mlo = l * C;
            const int mhi = (mlo + C < k) ? (mlo + C) : k;
            i00 = i10 = i01 = 0x7FFFFFFF;
            if (act && mlo < mhi) {
                scanChunk(Q4, i, j, k, mlo, mhi, vL, vR,
                          v00, v10, v01, v11, i00, i10, i01, i11);
            }
        }

        // Prefetch next step's mapping + vL/vR (overlaps reduction + barrier).
        if (k + 1 < kN) {
            mapK(k + 1, tid, ci, cj, cact, cP, clp);
            vL = cact ? v[cj * kN + ci] : 0.f;
            vR = cact ? v[ci * kN + cj] : 0.f;
        }

        if (P == 1) {
            if (act) {
                writeCell(Q4, wsBT, i, j, k, v00, v10, v01, v11, i00, i10, i01, i11);
            }
        } else {
            const bool waveActive = (((tid & ~63) >> lp) < R);  // wave-uniform
            if (waveActive) {
                const int l = tid & (P - 1);
                // group max: k>16 => P>=4? (P>=8 for k>16 actually); stages guarded
                float g00 = dppMax<0x4E>(dppMax<0xB1>(v00));
                float g10 = dppMax<0x4E>(dppMax<0xB1>(v10));
                float g01 = dppMax<0x4E>(dppMax<0xB1>(v01));
                float g11 = dppMax<0x4E>(dppMax<0xB1>(v11));
                if (P >= 8) {
                    g00 = dppMax<0x141>(g00); g10 = dppMax<0x141>(g10);
                    g01 = dppMax<0x141>(g01); g11 = dppMax<0x141>(g11);
                }
                if (P >= 16) {
                    g00 = dppMax<0x140>(g00); g10 = dppMax<0x140>(g10);
                    g01 = dppMax<0x140>(g01); g11 = dppMax<0x140>(g11);
                }
                if (P >= 32) {
                    g00 = swzMax16(g00); g10 = swzMax16(g10);
                    g01 = swzMax16(g01); g11 = swzMax16(g11);
                }
                if (P == 64) {
                    g00 = fmaxf(g00, __shfl_xor(g00, 32, 64));
                    g10 = fmaxf(g10, __shfl_xor(g10, 32, 64));
                    g01 = fmaxf(g01, __shfl_xor(g01, 32, 64));
                    g11 = fmaxf(g11, __shfl_xor(g11, 32, 64));
                }
                // earliest-m via ballot (contiguous chunks => lane order == m order;
                // empty lanes hold -3e38, can never equal group max >= -19998)
                const int grpStart = laneId & ~(P - 1);
                const uint64_t gmask =
                    (P == 64) ? ~0ull : (((1ull << P) - 1ull) << grpStart);
                const uint64_t m0 = __ballot(v00 == g00) & gmask;
                const uint64_t m1 = __ballot(v10 == g10) & gmask;
                const uint64_t m2 = __ballot(v01 == g01) & gmask;
                const uint64_t m3 = __ballot(v11 == g11) & gmask;
                const int r00 = __shfl(i00, __ffsll((unsigned long long)m0) - 1, 64);
                const int r10 = __shfl(i10, __ffsll((unsigned long long)m1) - 1, 64);
                const int r01 = __shfl(i01, __ffsll((unsigned long long)m2) - 1, 64);
                const int r11 = __shfl(i11, __ffsll((unsigned long long)m3) - 1, 64);
                if (act && l == 0) {
                    writeCell(Q4, wsBT, i, j, k, g00, g10, g01, g11, r00, r10, r01, r11);
                }
            }
        }
        // LDS-only barrier: wsBT stores & prefetch loads stay in flight.
        ldsBarrier();
    }

    // Full barrier (drains vmcnt) before reading wsBT back.
    __syncthreads();

    // ---- epilogue: emit full [N][N][2][2] scores + backtrace, coalesced ----
    float4* gS4 = (float4*)(outS + (size_t)b * kN * kN * 4);
    float4* gB4 = (float4*)(outBT + (size_t)b * kN * kN * 4);
    const float4 negq = make_float4(kNeg, kNeg, kNeg, kNeg);
    for (int c = tid; c < kN * kN; c += kThreads) {
        const int i = c >> 7, j = c & (kN - 1);
        if (i < j) {
            const float4 q = Q4[colBaseD(j) + i];
            gS4[c] = make_float4(q.x, q.z, q.w, q.y);  // {s00, s01, s10, s11}
            const uint32_t p = wsBT[rowBase(i) + (j - i - 1)];
            gB4[c] = make_float4((float)(p & 255u), (float)((p >> 8) & 255u),
                                 (float)((p >> 16) & 255u), (float)(p >> 24));
        } else if (i == j) {
            gS4[c] = zeroq;
            gB4[c] = zeroq;
        } else {
            gS4[c] = negq;
            gB4[c] = zeroq;
        }
    }
}

extern "C" void kernel_launch(void* const* d_in, const int* in_sizes, int n_in,
                              void* d_out, int out_size, void* d_ws, size_t ws_size,
                              hipStream_t stream) {
    (void)n_in; (void)out_size; (void)ws_size;
    const float* vinfo = (const float*)d_in[0];  // fp32 [B][N][N]
    const int B = in_sizes[1];                   // b_buffer_size has B elements
    float* outS = (float*)d_out;
    float* outBT = outS + (size_t)B * kN * kN * 4;
    uint32_t* btPacked = (uint32_t*)d_ws;        // needs B*kTri*4 = ~2.1 MB

    hipFuncSetAttribute(reinterpret_cast<const void*>(eisner_dp),
                        hipFuncAttributeMaxDynamicSharedMemorySize, kDynLds);

    eisner_dp<<<dim3(B), dim3(kThreads), kDynLds, stream>>>(vinfo, outS, outBT, btPacked);
}